// Round 1
// baseline (4333.697 us; speedup 1.0000x reference)
//
#include <hip/hip_runtime.h>
#include <hip/hip_bf16.h>

#define NE 1000000
#define NN 50000
#define D 64

// order-preserving float<->uint encoding for atomicMax on floats
__device__ __forceinline__ unsigned fenc(float f){
  unsigned u = __float_as_uint(f);
  return (u & 0x80000000u) ? ~u : (u | 0x80000000u);
}
__device__ __forceinline__ float fdec(unsigned u){
  return (u & 0x80000000u) ? __uint_as_float(u & 0x7fffffffu) : __uint_as_float(~u);
}

// ws layout (32-bit words):
// [0, NE)              e (attention logits)
// [NE, 2NE)            exp_e
// [2NE, 2NE+NN)        maxv (uint, order-encoded)
// [2NE+NN, 2NE+2NN)    denom
// [2NE+2NN, +NN*D)     p_av = x_v @ W_av^T
// total = 2e6 + 100000 + 3.2e6 floats = 21.2 MB

__global__ __launch_bounds__(256) void k_init(unsigned* __restrict__ maxv,
                                              float* __restrict__ denom){
  int i = blockIdx.x*256 + threadIdx.x;
  if (i < NN){ maxv[i] = 0x007FFFFFu; /* enc(-inf) */ denom[i] = 0.f; }
}

// h_self = x_v@W_vv^T + b_vv -> h_v;  p_av = x_v@W_av^T -> ws
__global__ __launch_bounds__(256) void k_node(const float* __restrict__ x_v,
    const float* __restrict__ W_vv, const float* __restrict__ b_vv,
    const float* __restrict__ W_av, float* __restrict__ h_v, float* __restrict__ p_av){
  int lane = threadIdx.x & 63;
  int n = (blockIdx.x*256 + threadIdx.x) >> 6;   // wave-uniform node id
  if (n >= NN) return;
  const float* xr = x_v + (size_t)n*D;
  float a0 = b_vv[lane], a1 = 0.f;
  #pragma unroll 8
  for (int k = 0; k < D; k++){
    float xk = xr[k];                       // wave-uniform -> scalarizable
    a0 += xk * W_vv[lane*D + k];            // 16KB matrix, L1-resident
    a1 += xk * W_av[lane*D + k];
  }
  h_v[(size_t)n*D + lane]  = a0;
  p_av[(size_t)n*D + lane] = a1;
}

// attention logit per edge + segment max into dst
__global__ __launch_bounds__(256) void k_att(const float* __restrict__ x_a,
    const int* __restrict__ dst, const float* __restrict__ W_att,
    const float* __restrict__ b_att, float* __restrict__ elog,
    unsigned* __restrict__ maxv){
  int i = blockIdx.x*256 + threadIdx.x;
  if (i >= NE) return;
  const float4* r = (const float4*)(x_a + (size_t)i*D);
  const float4* w = (const float4*)W_att;   // uniform -> scalar loads
  float acc = b_att[0];
  #pragma unroll
  for (int c = 0; c < 16; c++){
    float4 v = r[c]; float4 ww = w[c];
    acc += v.x*ww.x + v.y*ww.y + v.z*ww.z + v.w*ww.w;
  }
  elog[i] = acc;
  atomicMax(&maxv[dst[i]], fenc(acc));
}

// exp(e - max[dst]) + segment sum
__global__ __launch_bounds__(256) void k_exp(const float* __restrict__ elog,
    const int* __restrict__ dst, const unsigned* __restrict__ maxv,
    float* __restrict__ exp_e, float* __restrict__ denom){
  int i = blockIdx.x*256 + threadIdx.x;
  if (i >= NE) return;
  int d = dst[i];
  float ex = __expf(elog[i] - fdec(maxv[d]));
  exp_e[i] = ex;
  unsafeAtomicAdd(&denom[d], ex);
}

// main edge kernel: per-wave chunk of 32 edges.
// lane = (r, jhalf): r = lane&31 -> edge, jhalf = lane>>5 -> output cols [32*jhalf, +32)
// accV/accA: 32 fp32 regs each. W transposed in LDS (broadcast reads),
// x rows transposed in LDS (stride 32: reads conflict-free broadcast pairs).
__global__ __launch_bounds__(256) void k_edge(const float* __restrict__ x_a,
    const int* __restrict__ src, const int* __restrict__ dst,
    const float* __restrict__ W_va, const float* __restrict__ W_aa,
    const float* __restrict__ b_aa, const float* __restrict__ exp_e,
    const float* __restrict__ denom, const float* __restrict__ p_av,
    float* __restrict__ h_v, float* __restrict__ h_a){
  __shared__ float wvaT[D*D];       // wvaT[k*64 + j] = W_va[j][k]   (16 KB)
  __shared__ float waaT[D*D];       // 16 KB
  __shared__ float xT[4][D*32];     // per-wave: xT[k*32 + r] = x_a[e0+r][k] (32 KB)
  // total LDS = 64 KB -> 2 blocks/CU

  for (int t = threadIdx.x; t < D*D; t += 256){
    int j = t >> 6, k = t & 63;
    wvaT[k*D + j] = W_va[t];
    waaT[k*D + j] = W_aa[t];
  }

  int lane = threadIdx.x & 63;
  int wv   = threadIdx.x >> 6;
  int chunk = blockIdx.x*4 + wv;
  int e0 = chunk*32;
  bool live = (e0 < NE);
  int ee0 = live ? e0 : 0;          // ghost waves recompute chunk 0, stores masked
  float* xs = xT[wv];

  // stage 32 rows transposed; global reads coalesced (wave reads 4 rows/iter)
  {
    int r4 = lane >> 4;             // 0..3
    int c  = (lane & 15) * 4;       // 0,4,...,60
    #pragma unroll
    for (int i = 0; i < 8; i++){
      int r = i*4 + r4;
      float4 v = *(const float4*)(x_a + (size_t)(ee0 + r)*D + c);
      xs[(c+0)*32 + r] = v.x;
      xs[(c+1)*32 + r] = v.y;
      xs[(c+2)*32 + r] = v.z;
      xs[(c+3)*32 + r] = v.w;
    }
  }
  __syncthreads();   // all threads reach this (no early returns)

  int r  = lane & 31;
  int jb = (lane >> 5) * 32;
  int e  = ee0 + r;

  float accV[32], accA[32];
  #pragma unroll
  for (int j = 0; j < 32; j++){ accV[j] = 0.f; accA[j] = 0.f; }

  #pragma unroll 4
  for (int k = 0; k < D; k++){
    float xk = xs[k*32 + r];
    const float4* wva = (const float4*)(wvaT + k*D + jb);
    const float4* waa = (const float4*)(waaT + k*D + jb);
    #pragma unroll
    for (int jj = 0; jj < 8; jj++){
      float4 a = wva[jj], b = waa[jj];
      accV[4*jj+0] += xk*a.x; accV[4*jj+1] += xk*a.y;
      accV[4*jj+2] += xk*a.z; accV[4*jj+3] += xk*a.w;
      accA[4*jj+0] += xk*b.x; accA[4*jj+1] += xk*b.y;
      accA[4*jj+2] += xk*b.z; accA[4*jj+3] += xk*b.w;
    }
  }

  int s  = src[e];
  int d2 = dst[e];
  float attn = exp_e[e] / denom[d2];

  if (live){
    float* hv = h_v + (size_t)d2*D + jb;
    #pragma unroll
    for (int j = 0; j < 32; j++) unsafeAtomicAdd(&hv[j], accV[j]*attn);

    float4*       ha = (float4*)(h_a + (size_t)e*D + jb);
    const float4* ps = (const float4*)(p_av + (size_t)s*D  + jb);
    const float4* pd = (const float4*)(p_av + (size_t)d2*D + jb);
    const float4* bb = (const float4*)(b_aa + jb);
    #pragma unroll
    for (int jj = 0; jj < 8; jj++){
      float4 v1 = ps[jj], v2 = pd[jj], v3 = bb[jj], o;
      o.x = accA[4*jj+0] + v1.x + v2.x + v3.x;
      o.y = accA[4*jj+1] + v1.y + v2.y + v3.y;
      o.z = accA[4*jj+2] + v1.z + v2.z + v3.z;
      o.w = accA[4*jj+3] + v1.w + v2.w + v3.w;
      ha[jj] = o;
    }
  }
}

extern "C" void kernel_launch(void* const* d_in, const int* in_sizes, int n_in,
                              void* d_out, int out_size, void* d_ws, size_t ws_size,
                              hipStream_t stream){
  const float* x_v   = (const float*)d_in[0];
  const float* x_a   = (const float*)d_in[1];
  const int*   arc   = (const int*)  d_in[2];
  const float* W_vv  = (const float*)d_in[3];
  const float* b_vv  = (const float*)d_in[4];
  const float* W_va  = (const float*)d_in[5];
  const float* W_att = (const float*)d_in[6];
  const float* b_att = (const float*)d_in[7];
  const float* W_aa  = (const float*)d_in[8];
  const float* b_aa  = (const float*)d_in[9];
  const float* W_av  = (const float*)d_in[10];

  float* out = (float*)d_out;
  float* h_v = out;                        // [NN, D]
  float* h_a = out + (size_t)NN*D;         // [NE, D]

  float*    wsf   = (float*)d_ws;
  float*    elog  = wsf;
  float*    exp_e = wsf + NE;
  unsigned* maxv  = (unsigned*)(wsf + 2*(size_t)NE);
  float*    denom = wsf + 2*(size_t)NE + NN;
  float*    p_av  = wsf + 2*(size_t)NE + 2*NN;

  const int* srcp = arc;
  const int* dstp = arc + NE;

  hipLaunchKernelGGL(k_init, dim3((NN+255)/256), dim3(256), 0, stream, maxv, denom);
  hipLaunchKernelGGL(k_node, dim3(NN*D/256), dim3(256), 0, stream,
                     x_v, W_vv, b_vv, W_av, h_v, p_av);
  hipLaunchKernelGGL(k_att, dim3((NE+255)/256), dim3(256), 0, stream,
                     x_a, dstp, W_att, b_att, elog, maxv);
  hipLaunchKernelGGL(k_exp, dim3((NE+255)/256), dim3(256), 0, stream,
                     elog, dstp, maxv, exp_e, denom);
  hipLaunchKernelGGL(k_edge, dim3((NE/32 + 3)/4), dim3(256), 0, stream,
                     x_a, srcp, dstp, W_va, W_aa, b_aa, exp_e, denom, p_av, h_v, h_a);
}

// Round 2
// 1256.262 us; speedup vs baseline: 3.4497x; 3.4497x over previous
//
#include <hip/hip_runtime.h>
#include <hip/hip_bf16.h>

#define NE 1000000
#define NN 50000
#define D 64

// order-preserving float<->uint encoding for atomicMax on floats
__device__ __forceinline__ unsigned fenc(float f){
  unsigned u = __float_as_uint(f);
  return (u & 0x80000000u) ? ~u : (u | 0x80000000u);
}
__device__ __forceinline__ float fdec(unsigned u){
  return (u & 0x80000000u) ? __uint_as_float(u & 0x7fffffffu) : __uint_as_float(~u);
}

__global__ __launch_bounds__(256) void k_init(unsigned* __restrict__ maxv,
                                              float* __restrict__ denom,
                                              int* __restrict__ counts){
  int i = blockIdx.x*256 + threadIdx.x;
  if (i < NN){ maxv[i] = 0x007FFFFFu; /* enc(-inf) */ denom[i] = 0.f; counts[i] = 0; }
}

// h_self = x_v@W_vv^T + b_vv -> h_v;  p_av = x_v@W_av^T -> ws
__global__ __launch_bounds__(256) void k_node(const float* __restrict__ x_v,
    const float* __restrict__ W_vv, const float* __restrict__ b_vv,
    const float* __restrict__ W_av, float* __restrict__ h_v, float* __restrict__ p_av){
  int lane = threadIdx.x & 63;
  int n = (blockIdx.x*256 + threadIdx.x) >> 6;   // wave-uniform node id
  if (n >= NN) return;
  const float* xr = x_v + (size_t)n*D;
  float a0 = b_vv[lane], a1 = 0.f;
  #pragma unroll 8
  for (int k = 0; k < D; k++){
    float xk = xr[k];                       // wave-uniform
    a0 += xk * W_vv[lane*D + k];            // 16KB matrix, cache-resident
    a1 += xk * W_av[lane*D + k];
  }
  h_v[(size_t)n*D + lane]  = a0;
  p_av[(size_t)n*D + lane] = a1;
}

// Fused edge pass 1: h_a = x_a@W_aa^T + b_aa + p_av[src] + p_av[dst]
//                    elog = x_a@W_att^T + b_att, segment-max, histogram.
// Per-wave chunk of 32 edges; lane=(r,jhalf).
__global__ __launch_bounds__(256) void k_fuse_edge(const float* __restrict__ x_a,
    const int* __restrict__ src, const int* __restrict__ dst,
    const float* __restrict__ W_aa, const float* __restrict__ b_aa,
    const float* __restrict__ W_att, const float* __restrict__ b_att,
    const float* __restrict__ p_av, float* __restrict__ h_a,
    float* __restrict__ elog, unsigned* __restrict__ maxv, int* __restrict__ counts){
  __shared__ float waaT[D*D];       // waaT[k*64 + j] = W_aa[j][k]   (16 KB)
  __shared__ float xT[4][D*32];     // per-wave transposed x rows    (32 KB)
  __shared__ float watt[D];
  // LDS ~48.3 KB -> 3 blocks/CU

  for (int t = threadIdx.x; t < D*D; t += 256){
    int j = t >> 6, k = t & 63;
    waaT[k*D + j] = W_aa[t];
  }
  if (threadIdx.x < D) watt[threadIdx.x] = W_att[threadIdx.x];

  int lane = threadIdx.x & 63;
  int wv   = threadIdx.x >> 6;
  int chunk = blockIdx.x*4 + wv;
  int e0 = chunk*32;
  bool live = (e0 < NE);
  int ee0 = live ? e0 : 0;
  float* xs = xT[wv];

  {
    int r4 = lane >> 4;
    int c  = (lane & 15) * 4;
    #pragma unroll
    for (int i = 0; i < 8; i++){
      int r = i*4 + r4;
      float4 v = *(const float4*)(x_a + (size_t)(ee0 + r)*D + c);
      xs[(c+0)*32 + r] = v.x;
      xs[(c+1)*32 + r] = v.y;
      xs[(c+2)*32 + r] = v.z;
      xs[(c+3)*32 + r] = v.w;
    }
  }
  __syncthreads();

  int r  = lane & 31;
  int jb = (lane >> 5) * 32;
  int e  = ee0 + r;

  float accA[32];
  #pragma unroll
  for (int j = 0; j < 32; j++) accA[j] = 0.f;
  float el = 0.f;

  #pragma unroll 4
  for (int k = 0; k < D; k++){
    float xk = xs[k*32 + r];
    el += xk * watt[k];
    const float4* waa = (const float4*)(waaT + k*D + jb);
    #pragma unroll
    for (int jj = 0; jj < 8; jj++){
      float4 b = waa[jj];
      accA[4*jj+0] += xk*b.x; accA[4*jj+1] += xk*b.y;
      accA[4*jj+2] += xk*b.z; accA[4*jj+3] += xk*b.w;
    }
  }

  int s  = src[e];
  int d2 = dst[e];

  if (live){
    if (lane < 32){
      float eL = el + b_att[0];
      elog[e] = eL;
      atomicMax(&maxv[d2], fenc(eL));
      atomicAdd(&counts[d2], 1);
    }
    float4*       ha = (float4*)(h_a + (size_t)e*D + jb);
    const float4* ps = (const float4*)(p_av + (size_t)s*D  + jb);
    const float4* pd = (const float4*)(p_av + (size_t)d2*D + jb);
    const float4* bb = (const float4*)(b_aa + jb);
    #pragma unroll
    for (int jj = 0; jj < 8; jj++){
      float4 v1 = ps[jj], v2 = pd[jj], v3 = bb[jj], o;
      o.x = accA[4*jj+0] + v1.x + v2.x + v3.x;
      o.y = accA[4*jj+1] + v1.y + v2.y + v3.y;
      o.z = accA[4*jj+2] + v1.z + v2.z + v3.z;
      o.w = accA[4*jj+3] + v1.w + v2.w + v3.w;
      ha[jj] = o;
    }
  }
}

// exp(e - max[dst]) + segment sum
__global__ __launch_bounds__(256) void k_exp(const float* __restrict__ elog,
    const int* __restrict__ dst, const unsigned* __restrict__ maxv,
    float* __restrict__ exp_e, float* __restrict__ denom){
  int i = blockIdx.x*256 + threadIdx.x;
  if (i >= NE) return;
  int d = dst[i];
  float ex = __expf(elog[i] - fdec(maxv[d]));
  exp_e[i] = ex;
  unsafeAtomicAdd(&denom[d], ex);
}

// --- 3-stage exclusive scan of counts[NN] -> offsets[NN+1], cursor copy ---
__global__ __launch_bounds__(256) void k_scan_a(const int* __restrict__ counts,
    int* __restrict__ offsets, int* __restrict__ blocksum){
  __shared__ int sm[256];
  int t = threadIdx.x;
  int idx = blockIdx.x*256 + t;
  int v = (idx < NN) ? counts[idx] : 0;
  sm[t] = v;
  __syncthreads();
  #pragma unroll
  for (int dd = 1; dd < 256; dd <<= 1){
    int x = (t >= dd) ? sm[t-dd] : 0;
    __syncthreads();
    sm[t] += x;
    __syncthreads();
  }
  if (idx < NN) offsets[idx] = sm[t] - v;         // local exclusive
  if (t == 255) blocksum[blockIdx.x] = sm[255];
}

__global__ __launch_bounds__(256) void k_scan_b(const int* __restrict__ blocksum,
    int* __restrict__ blockoff, int* __restrict__ offsets, int nblk){
  __shared__ int sm[256];
  int t = threadIdx.x;
  int v = (t < nblk) ? blocksum[t] : 0;
  sm[t] = v;
  __syncthreads();
  #pragma unroll
  for (int dd = 1; dd < 256; dd <<= 1){
    int x = (t >= dd) ? sm[t-dd] : 0;
    __syncthreads();
    sm[t] += x;
    __syncthreads();
  }
  if (t < nblk) blockoff[t] = sm[t] - v;
  if (t == 0) offsets[NN] = NE;
}

__global__ __launch_bounds__(256) void k_scan_c(int* __restrict__ offsets,
    int* __restrict__ cursor, const int* __restrict__ blockoff){
  int idx = blockIdx.x*256 + threadIdx.x;
  if (idx < NN){
    int o = offsets[idx] + blockoff[blockIdx.x];
    offsets[idx] = o;
    cursor[idx] = o;
  }
}

// scatter edge ids (and exp values) into dst-sorted order
__global__ __launch_bounds__(256) void k_scatter(const int* __restrict__ dst,
    const float* __restrict__ exp_e, int* __restrict__ cursor,
    int* __restrict__ eid, float* __restrict__ esort){
  int i = blockIdx.x*256 + threadIdx.x;
  if (i >= NE) return;
  int d = dst[i];
  int pos = atomicAdd(&cursor[d], 1);
  eid[pos] = i;
  esort[pos] = exp_e[i];
}

// per-node gather: y = (1/denom) * sum_e esort*x_a[eid];  h_v += W_va @ y
__global__ __launch_bounds__(256) void k_gather(const float* __restrict__ x_a,
    const int* __restrict__ eid, const float* __restrict__ esort,
    const int* __restrict__ offsets, const float* __restrict__ denom,
    const float* __restrict__ W_va, float* __restrict__ h_v){
  __shared__ float wT[D*65];        // wT[k*65+j] = W_va[j][k], stride 65 kills write conflicts
  __shared__ float yb[4][D];
  for (int t = threadIdx.x; t < D*D; t += 256){
    int j = t >> 6, k = t & 63;
    wT[k*65 + j] = W_va[t];
  }
  __syncthreads();
  int lane = threadIdx.x & 63;
  int wv   = threadIdx.x >> 6;
  int n = blockIdx.x*4 + wv;        // exact: 12500*4 == NN
  int start = offsets[n], end = offsets[n+1];
  float y = 0.f;
  int i = start;
  for (; i + 2 <= end; i += 2){
    int e0 = eid[i], e1 = eid[i+1];
    float a0 = esort[i], a1 = esort[i+1];
    float x0 = x_a[(size_t)e0*D + lane];
    float x1 = x_a[(size_t)e1*D + lane];
    y += a0*x0 + a1*x1;
  }
  if (i < end) y += esort[i] * x_a[(size_t)eid[i]*D + lane];
  float inv = (end > start) ? 1.0f / denom[n] : 0.f;
  y *= inv;
  yb[wv][lane] = y;
  __builtin_amdgcn_wave_barrier();  // same-wave LDS RAW; keep compiler honest
  float acc = 0.f;
  #pragma unroll 8
  for (int k = 0; k < D; k++) acc += yb[wv][k] * wT[k*65 + lane];
  h_v[(size_t)n*D + lane] += acc;
}

extern "C" void kernel_launch(void* const* d_in, const int* in_sizes, int n_in,
                              void* d_out, int out_size, void* d_ws, size_t ws_size,
                              hipStream_t stream){
  const float* x_v   = (const float*)d_in[0];
  const float* x_a   = (const float*)d_in[1];
  const int*   arc   = (const int*)  d_in[2];
  const float* W_vv  = (const float*)d_in[3];
  const float* b_vv  = (const float*)d_in[4];
  const float* W_va  = (const float*)d_in[5];
  const float* W_att = (const float*)d_in[6];
  const float* b_att = (const float*)d_in[7];
  const float* W_aa  = (const float*)d_in[8];
  const float* b_aa  = (const float*)d_in[9];
  const float* W_av  = (const float*)d_in[10];

  float* out = (float*)d_out;
  float* h_v = out;                        // [NN, D]
  float* h_a = out + (size_t)NN*D;         // [NE, D]

  // ws layout (32-bit words)
  float*    wsf      = (float*)d_ws;
  float*    elog     = wsf;                                  // NE
  float*    exp_e    = wsf + NE;                             // NE
  unsigned* maxv     = (unsigned*)(wsf + 2*(size_t)NE);      // NN
  float*    denom    = wsf + 2*(size_t)NE + NN;              // NN
  int*      counts   = (int*)(wsf + 2*(size_t)NE + 2*NN);    // NN
  int*      offsets  = counts + NN;                          // NN+1
  int*      cursor   = offsets + NN + 1;                     // NN
  int*      blocksum = cursor + NN;                          // 256
  int*      blockoff = blocksum + 256;                       // 256
  int*      eid      = blockoff + 256;                       // NE
  float*    esort    = (float*)(eid + NE);                   // NE
  float*    p_av     = esort + NE;                           // NN*D
  // total ~30.2 MB

  const int* srcp = arc;
  const int* dstp = arc + NE;
  const int NB = (NN + 255)/256;  // 196

  hipLaunchKernelGGL(k_init, dim3(NB), dim3(256), 0, stream, maxv, denom, counts);
  hipLaunchKernelGGL(k_node, dim3(NN*D/256), dim3(256), 0, stream,
                     x_v, W_vv, b_vv, W_av, h_v, p_av);
  hipLaunchKernelGGL(k_fuse_edge, dim3((NE/32 + 3)/4), dim3(256), 0, stream,
                     x_a, srcp, dstp, W_aa, b_aa, W_att, b_att, p_av, h_a,
                     elog, maxv, counts);
  hipLaunchKernelGGL(k_exp, dim3((NE+255)/256), dim3(256), 0, stream,
                     elog, dstp, maxv, exp_e, denom);
  hipLaunchKernelGGL(k_scan_a, dim3(NB), dim3(256), 0, stream, counts, offsets, blocksum);
  hipLaunchKernelGGL(k_scan_b, dim3(1), dim3(256), 0, stream, blocksum, blockoff, offsets, NB);
  hipLaunchKernelGGL(k_scan_c, dim3(NB), dim3(256), 0, stream, offsets, cursor, blockoff);
  hipLaunchKernelGGL(k_scatter, dim3((NE+255)/256), dim3(256), 0, stream,
                     dstp, exp_e, cursor, eid, esort);
  hipLaunchKernelGGL(k_gather, dim3(NN/4), dim3(256), 0, stream,
                     x_a, eid, esort, offsets, denom, W_va, h_v);
}